// Round 10
// baseline (209.304 us; speedup 1.0000x reference)
//
#include <hip/hip_runtime.h>
#include <hip/hip_bf16.h>

#define NLB 4096
#define NULB 6144
#define NROWS 16384   // 4096 + 2*6144
#define DD 128
#define NC 10
#define VW 12                // P12 row width: 10 numerators + denom + pad
#define SEG 16
#define JSEG (NROWS / SEG)   // 1024
#define BI 256               // i-rows per block (4 waves x 64)
#define BJ 128               // j-rows per LDS tile
#define SQRTC 1.6986437f     // sqrt(2*log2(e)); F pre-scaled so exp(2*dot)=2^cfr

typedef __bf16 bf16_t;
typedef _Float16 f16_t;
typedef bf16_t bf16x8 __attribute__((ext_vector_type(8)));
typedef f16_t f16x8 __attribute__((ext_vector_type(8)));
typedef float f32x4 __attribute__((ext_vector_type(4)));
typedef short i16x2 __attribute__((ext_vector_type(2)));
typedef unsigned int u32;

// F global layout = swizzled LDS image, 128-row tiles:
//   element index(row, chunk c0..15) =
//     (row>>7)*16384 + ((row&127)*16 + (c ^ (row&15)))*8   (8 bf16 per chunk)
__device__ __forceinline__ size_t fidx(int row, int c) {
  return ((size_t)(row >> 7) << 14) + (size_t)(((row & 127) * 16 + (c ^ (row & 15))) << 3);
}

// pack two f16(2^c) values into one dword via the f16 int-hack:
// bits16 = round(1024*c + 1024*(15-0.0436)); staircase rel err ~1.5%,
// common-mode between numerator and ones-column denominator (R9: absmax-neutral).
__device__ __forceinline__ u32 packexp2(float c0, float c1) {
#if __has_builtin(__builtin_amdgcn_cvt_pknorm_i16)
  // fold /32767 of pknorm into the fma constants
  float y0 = fmaf(c0, 0.031251907f, 0.46740490f);
  float y1 = fmaf(c1, 0.031251907f, 0.46740490f);
  union { i16x2 p; u32 u; } cv;
  cv.p = __builtin_amdgcn_cvt_pknorm_i16(y0, y1);
  return cv.u;
#else
  u32 b0 = (u32)(int)fmaf(c0, 1024.0f, 15315.354f);
  u32 b1 = (u32)(int)fmaf(c1, 1024.0f, 15315.354f);
  return __builtin_amdgcn_perm(b1, b0, 0x05040100u);  // {lo16(b0), lo16(b1)}
#endif
}

// ================= fused prep =================
// blocks 0..1023   : L2-normalize 16 rows each of [lb;anchor;pos] -> scaled bf16
//                    F (swizzled-tile layout) + zero 192 floats of P12 each
// blocks 1024..1087: build f16 V fragments + per-block class-count partials
// VF layout: per 32-row group g, lane l=(q=l>>4, n=l&15), 16B chunk:
//   f16 V[g*32+q*4+d][n] d=0..3, then f16 V[g*32+16+q*4+d][n] d=0..3
//   -> f16 B-operand frag: k=q*8+{0..3} = even 16-row chunk, {4..7} = odd.
__global__ void kprep2(const float* __restrict__ lb, const float* __restrict__ an,
                       const float* __restrict__ po, const float* __restrict__ onehot,
                       const float* __restrict__ l1, const float* __restrict__ l2,
                       bf16_t* __restrict__ F, f16_t* __restrict__ VF,
                       float* __restrict__ clsPart, float* __restrict__ P12) {
  __shared__ float Vtmp[256 * 16];
  __shared__ float lcnt[NC];
  int b = blockIdx.x;
  int t = threadIdx.x;

  if (b < 1024) {
    if (t < 192) P12[(size_t)b * 192 + t] = 0.0f;  // 1024*192 = NROWS*VW
    int row = b * 16 + (t >> 4);
    int c = t & 15;
    const float* src;
    if (row < NLB) src = lb + (size_t)row * DD;
    else if (row < NLB + NULB) src = an + (size_t)(row - NLB) * DD;
    else src = po + (size_t)(row - NLB - NULB) * DD;
    float4 v0 = ((const float4*)src)[c * 2];
    float4 v1 = ((const float4*)src)[c * 2 + 1];
    float ss = v0.x*v0.x + v0.y*v0.y + v0.z*v0.z + v0.w*v0.w
             + v1.x*v1.x + v1.y*v1.y + v1.z*v1.z + v1.w*v1.w;
#pragma unroll
    for (int off = 8; off >= 1; off >>= 1) ss += __shfl_xor(ss, off);
    float inv = SQRTC / fmaxf(sqrtf(ss), 1e-12f);
    union { bf16_t h[8]; uint4 u; } pk;
    pk.h[0] = (bf16_t)(v0.x*inv); pk.h[1] = (bf16_t)(v0.y*inv);
    pk.h[2] = (bf16_t)(v0.z*inv); pk.h[3] = (bf16_t)(v0.w*inv);
    pk.h[4] = (bf16_t)(v1.x*inv); pk.h[5] = (bf16_t)(v1.y*inv);
    pk.h[6] = (bf16_t)(v1.z*inv); pk.h[7] = (bf16_t)(v1.w*inv);
    *(uint4*)(F + fidx(row, c)) = pk.u;
    return;
  }

  // ---- V build: 256 rows/block over all 16384 output rows ----
  if (t < NC) lcnt[t] = 0.0f;
  __syncthreads();
  int gid = (b - 1024) * 256 + t;
  float p[16];
  p[10] = 1.0f; p[11] = 0.f; p[12] = 0.f; p[13] = 0.f; p[14] = 0.f; p[15] = 0.f;
  if (gid < NLB) {
    int idx = 0;
#pragma unroll
    for (int c = 0; c < NC; ++c) {
      p[c] = onehot[(size_t)gid * NC + c];
      if (p[c] == 1.0f) idx = c;
    }
    atomicAdd(&lcnt[idx], 1.0f);
  } else {
    int r = (gid < NLB + NULB) ? (gid - NLB) : (gid - NLB - NULB);
    bool count = (gid < NLB + NULB);
    float a[NC], bb[NC];
#pragma unroll
    for (int c = 0; c < NC; ++c) { a[c] = l1[(size_t)r * NC + c]; bb[c] = l2[(size_t)r * NC + c]; }
    float m1 = a[0], m2 = bb[0];
#pragma unroll
    for (int c = 1; c < NC; ++c) { m1 = fmaxf(m1, a[c]); m2 = fmaxf(m2, bb[c]); }
    float s1 = 0.0f, s2 = 0.0f;
#pragma unroll
    for (int c = 0; c < NC; ++c) {
      s1 += expf(2.0f * (a[c] - m1));
      s2 += expf(2.0f * (bb[c] - m2));
    }
    bool take1 = (s1 <= s2);  // max(prob1)=1/s1 >= 1/s2=max(prob2)
    float g[NC];
#pragma unroll
    for (int c = 0; c < NC; ++c) g[c] = take1 ? a[c] : bb[c];
    float mg = g[0];
#pragma unroll
    for (int c = 1; c < NC; ++c) mg = fmaxf(mg, g[c]);
    float e[NC]; float sg = 0.0f;
#pragma unroll
    for (int c = 0; c < NC; ++c) { e[c] = expf(g[c] - mg); sg += e[c]; }
    float msk[NC];
#pragma unroll
    for (int c = 0; c < NC; ++c) msk[c] = ((e[c] / sg) >= 0.95f) ? g[c] : 0.0f;
    float mx = msk[0]; int mi = 0;
#pragma unroll
    for (int c = 1; c < NC; ++c) if (msk[c] > mx) { mx = msk[c]; mi = c; }
    if (count && mx != 0.0f) atomicAdd(&lcnt[mi], 2.0f);
    float mm = 2.0f * msk[0];
#pragma unroll
    for (int c = 1; c < NC; ++c) mm = fmaxf(mm, 2.0f * msk[c]);
    float q[NC]; float sp = 0.0f;
#pragma unroll
    for (int c = 0; c < NC; ++c) { q[c] = expf(2.0f * msk[c] - mm); sp += q[c]; }
#pragma unroll
    for (int c = 0; c < NC; ++c) p[c] = q[c] / sp;
  }
#pragma unroll
  for (int c = 0; c < 16; ++c) Vtmp[t * 16 + c] = p[c];
  __syncthreads();
  if (t < 16) clsPart[(size_t)(b - 1024) * 16 + t] = (t < NC) ? lcnt[t] : 0.0f;
  // scatter to VF f16 frag layout: 512 16B chunks/block, 2 per thread
  int gbase = (b - 1024) * 8;   // 8 groups of 32 rows per 256-row block
#pragma unroll
  for (int u = 0; u < 2; ++u) {
    int cid = u * 256 + t;       // 0..511
    int g = cid >> 6;            // local group 0..7
    int l = cid & 63;
    int q = l >> 4;
    int n = l & 15;
    union { f16_t h[8]; uint4 uu; } pk;
#pragma unroll
    for (int d = 0; d < 4; ++d) {
      pk.h[d]     = (f16_t)Vtmp[(g * 32      + q * 4 + d) * 16 + n];
      pk.h[4 + d] = (f16_t)Vtmp[(g * 32 + 16 + q * 4 + d) * 16 + n];
    }
    *(uint4*)(VF + ((size_t)(gbase + g) * 64 + l) * 8) = pk.uu;
  }
}

// ================= attention partials =================
// QK: mfma_16x16x32_bf16 (F pre-scaled: w = 2^cfr). PV: mfma_16x16x32_f16 with
// EVEN and ODD 16-row j-chunks paired in one MFMA (P_e at k=q*8+0..3, P_o at
// k=q*8+4..7 against f16 V rows) -> PV MFMA count halved vs R9, no dup movs.
// P packed by fma+cvt_pknorm_i16 (f16 int-hack exp2, ~12 VALU-cyc/QK-tile).
// Staging via async global_load_lds. LDS 36864 B -> 4 blocks/CU, grid 1024.
__launch_bounds__(256, 4)
__global__ void kattn(const bf16_t* __restrict__ F, const f16_t* __restrict__ VF,
                      float* __restrict__ P12) {
  __shared__ bf16_t Fs[BJ * 128];   // 32 KB, swizzled tile image
  __shared__ uint4 Vs4[256];        // 4 KB f16 V frags (4 groups of 32 rows)
  int t = threadIdx.x;
  int lane = t & 63;
  int wave = t >> 6;    // 0..3
  int q = lane >> 4;    // 0..3
  int r = lane & 15;    // 0..15
  int i0 = blockIdx.x * BI + wave * 64;
  int jbase = blockIdx.y * JSEG;

  // stationary B-frags: 4 i-sets x 16 rows (from swizzled global layout)
  bf16x8 bfr[4][4];
#pragma unroll
  for (int s = 0; s < 4; ++s)
#pragma unroll
    for (int kk = 0; kk < 4; ++kk)
      bfr[s][kk] = *(const bf16x8*)(F + fidx(i0 + s * 16 + r, kk * 4 + q));

  f32x4 acc[4];
#pragma unroll
  for (int s = 0; s < 4; ++s) acc[s] = (f32x4){0.f, 0.f, 0.f, 0.f};

  for (int jt = 0; jt < JSEG; jt += BJ) {
    int j0 = jbase + jt;
    __syncthreads();
    // ---- async stage F tile (32 KB, 8 instr/wave) + V tile (4 KB, 1) ----
    {
      const uint4* srcF = (const uint4*)(F + ((size_t)(j0 >> 7) << 14));
#pragma unroll
      for (int k = 0; k < 8; ++k) {
        int off = ((k * 4 + wave) << 6) + lane;   // 16B-chunk idx 0..2047
        __builtin_amdgcn_global_load_lds(
            (const __attribute__((address_space(1))) uint4*)(srcF + off),
            (__attribute__((address_space(3))) uint4*)((uint4*)Fs + off), 16, 0, 0);
      }
      const uint4* srcV = (const uint4*)(VF + ((size_t)(j0 >> 5) << 9));
      __builtin_amdgcn_global_load_lds(
          (const __attribute__((address_space(1))) uint4*)(srcV + t),
          (__attribute__((address_space(3))) uint4*)(Vs4 + t), 16, 0, 0);
    }
    __syncthreads();  // implicit vmcnt(0) drain: data resident

#pragma unroll
    for (int jp = 0; jp < BJ / 32; ++jp) {   // pairs of 16-row j-chunks
      // A-frags for even (rows jp*32+r) and odd (rows jp*32+16+r) chunks
      bf16x8 ae[4], ao[4];
      const bf16_t* fse = &Fs[(jp * 32 + r) * 128];
#pragma unroll
      for (int kk = 0; kk < 4; ++kk) {
        ae[kk] = *(const bf16x8*)(fse + ((kk * 4 + q) ^ r) * 8);
        ao[kk] = *(const bf16x8*)(fse + 16 * 128 + ((kk * 4 + q) ^ r) * 8);
      }
      // f16 V B-frag: k=q*8+{0..3} = even-chunk rows, {4..7} = odd-chunk rows
      union { uint4 qd; f16x8 v; } bv;
      bv.qd = Vs4[jp * 64 + lane];
#pragma unroll
      for (int s = 0; s < 4; ++s) {
        f32x4 ce = {0.f, 0.f, 0.f, 0.f};
        f32x4 co = {0.f, 0.f, 0.f, 0.f};
#pragma unroll
        for (int kk = 0; kk < 4; ++kk) {
          ce = __builtin_amdgcn_mfma_f32_16x16x32_bf16(ae[kk], bfr[s][kk], ce, 0, 0, 0);
          co = __builtin_amdgcn_mfma_f32_16x16x32_bf16(ao[kk], bfr[s][kk], co, 0, 0, 0);
        }
        union { u32 u[4]; f16x8 v; } pf;
        pf.u[0] = packexp2(ce[0], ce[1]);
        pf.u[1] = packexp2(ce[2], ce[3]);
        pf.u[2] = packexp2(co[0], co[1]);
        pf.u[3] = packexp2(co[2], co[3]);
        acc[s] = __builtin_amdgcn_mfma_f32_16x16x32_f16(pf.v, bv.v, acc[s], 0, 0, 0);
      }
    }
  }

  // acc[s] lane(q,r) reg rg = partial[row = i0+s*16+q*4+rg][col = r]
  if (r < 11) {
#pragma unroll
    for (int s = 0; s < 4; ++s) {
      float* op = P12 + (size_t)(i0 + s * 16 + q * 4) * VW + r;
      atomicAdd(&op[0 * VW], acc[s][0]);
      atomicAdd(&op[1 * VW], acc[s][1]);
      atomicAdd(&op[2 * VW], acc[s][2]);
      atomicAdd(&op[3 * VW], acc[s][3]);
    }
  }
}

// ---------------- finalize: class-count reduce + divides ----------------
__global__ void kfinal(float* __restrict__ out, const float* __restrict__ P12,
                       const float* __restrict__ clsPart) {
  __shared__ float clsS[16];
  int t = threadIdx.x;
  if (t < 64) {
    const float4* cp = (const float4*)clsPart;  // 64 rows x 4 float4
    float4 c0 = cp[t * 4], c1 = cp[t * 4 + 1], c2 = cp[t * 4 + 2], c3 = cp[t * 4 + 3];
#pragma unroll
    for (int off = 32; off >= 1; off >>= 1) {
      c0.x += __shfl_xor(c0.x, off); c0.y += __shfl_xor(c0.y, off);
      c0.z += __shfl_xor(c0.z, off); c0.w += __shfl_xor(c0.w, off);
      c1.x += __shfl_xor(c1.x, off); c1.y += __shfl_xor(c1.y, off);
      c1.z += __shfl_xor(c1.z, off); c1.w += __shfl_xor(c1.w, off);
      c2.x += __shfl_xor(c2.x, off); c2.y += __shfl_xor(c2.y, off);
    }
    if (t == 0) {
      *(float4*)&clsS[0] = c0;
      *(float4*)&clsS[4] = c1;
      clsS[8] = c2.x; clsS[9] = c2.y;
      clsS[10] = 0.f; clsS[11] = 0.f; clsS[12] = 0.f;
      clsS[13] = 0.f; clsS[14] = 0.f; clsS[15] = 0.f;
    }
  }
  __syncthreads();
  float d[NC]; float tot = 0.0f;
#pragma unroll
  for (int c = 0; c < NC; ++c) { d[c] = clsS[c]; tot += d[c]; }
  int row = blockIdx.x * 256 + t;  // 64 blocks x 256
  const float* pr = P12 + (size_t)row * VW;
  float rs = 1.0f / pr[10];
  float* op = out + (size_t)row * NC;
#pragma unroll
  for (int c = 0; c < NC; ++c) {
    float den = (d[c] == 0.0f) ? tot : d[c];
    op[c] = pr[c] * rs / den;
  }
}

extern "C" void kernel_launch(void* const* d_in, const int* in_sizes, int n_in,
                              void* d_out, int out_size, void* d_ws, size_t ws_size,
                              hipStream_t stream) {
  const float* anchor   = (const float*)d_in[0];  // 6144x128
  const float* positive = (const float*)d_in[1];  // 6144x128
  const float* lbfeat   = (const float*)d_in[2];  // 4096x128
  const float* onehot   = (const float*)d_in[3];  // 4096x10
  const float* l1       = (const float*)d_in[4];  // 6144x10
  const float* l2       = (const float*)d_in[5];  // 6144x10
  float* out = (float*)d_out;                     // 16384x10

  char* ws = (char*)d_ws;
  bf16_t* F       = (bf16_t*)ws;                               // 4 MiB (swizzled tiles)
  f16_t*  VF      = (f16_t*)(ws + 4194304);                    // 512 KiB (f16 frags)
  float*  P12     = (float*)(ws + 4194304 + 524288);           // 768 KiB
  float*  clsPart = (float*)(ws + 4194304 + 524288 + 786432);  // 4 KiB

  kprep2<<<1088, 256, 0, stream>>>(lbfeat, anchor, positive, onehot, l1, l2,
                                   F, VF, clsPart, P12);
  kattn<<<dim3(NROWS / BI, SEG), 256, 0, stream>>>(F, VF, P12);
  kfinal<<<NROWS / 256, 256, 0, stream>>>(out, P12, clsPart);
}

// Round 11
// 141.843 us; speedup vs baseline: 1.4756x; 1.4756x over previous
//
#include <hip/hip_runtime.h>
#include <hip/hip_bf16.h>

#define NLB 4096
#define NULB 6144
#define NROWS 16384   // 4096 + 2*6144
#define DD 128
#define NC 10
#define VW 12                // P12 row width: 10 numerators + denom + pad
#define SEG 16
#define JSEG (NROWS / SEG)   // 1024
#define BI 256               // i-rows per block (4 waves x 64)
#define BJ 128               // j-rows per LDS tile
#define SQRTC 1.6986437f     // sqrt(2*log2(e)); F pre-scaled so exp(2*dot)=2^cfr
// f32 int-hack exp2 constants (fallback path)
#define FE_SCALE 8388608.0f
#define FE_BIAS  1.06498747e9f

typedef __bf16 bf16_t;
typedef bf16_t bf16x8 __attribute__((ext_vector_type(8)));
typedef float f32x4 __attribute__((ext_vector_type(4)));
typedef short i16x2 __attribute__((ext_vector_type(2)));
typedef unsigned int u32;

// F global layout = swizzled LDS image, 128-row tiles:
//   element index(row, chunk c0..15) =
//     (row>>7)*16384 + ((row&127)*16 + (c ^ (row&15)))*8   (8 bf16 per chunk)
__device__ __forceinline__ size_t fidx(int row, int c) {
  return ((size_t)(row >> 7) << 14) + (size_t)(((row & 127) * 16 + (c ^ (row & 15))) << 3);
}

// pack two bf16(2^c) into one dword: bf16 bits of 2^c ~= round(128*c + 16250.42)
// (linear-mantissa int-hack, +-0.3% staircase rel err, common-mode between
// numerator and ones-column denominator -- R9 proved absmax-neutral).
// pknorm folds round+clamp+pack into ONE VALU op: i16 = round(y*32767).
__device__ __forceinline__ u32 packexp2bf(float c0, float c1) {
#if __has_builtin(__builtin_amdgcn_cvt_pknorm_i16)
  float y0 = fmaf(c0, 3.9063692e-3f, 0.49593857f);   // 128/32767, 16250.42/32767
  float y1 = fmaf(c1, 3.9063692e-3f, 0.49593857f);
  union { i16x2 p; u32 u; } cv;
  cv.p = __builtin_amdgcn_cvt_pknorm_i16(y0, y1);
  return cv.u;
#else
  u32 b0 = (u32)(int)fmaf(c0, FE_SCALE, FE_BIAS);
  u32 b1 = (u32)(int)fmaf(c1, FE_SCALE, FE_BIAS);
  return __builtin_amdgcn_perm(b1, b0, 0x07060302u);  // {bf16(c0), bf16(c1)}
#endif
}

// ================= fused prep =================
// blocks 0..1023   : L2-normalize 16 rows each of [lb;anchor;pos] -> scaled bf16
//                    F (swizzled-tile layout) + zero 192 floats of P12 each
// blocks 1024..1087: build V fragments (interleaved hi/lo bf16) + per-block
//                    class-count partials (no global atomics, no pre-zero)
__global__ void kprep2(const float* __restrict__ lb, const float* __restrict__ an,
                       const float* __restrict__ po, const float* __restrict__ onehot,
                       const float* __restrict__ l1, const float* __restrict__ l2,
                       bf16_t* __restrict__ F, bf16_t* __restrict__ VF,
                       float* __restrict__ clsPart, float* __restrict__ P12) {
  __shared__ float Vtmp[256 * 16];
  __shared__ float lcnt[NC];
  int b = blockIdx.x;
  int t = threadIdx.x;

  if (b < 1024) {
    if (t < 192) P12[(size_t)b * 192 + t] = 0.0f;  // 1024*192 = NROWS*VW
    int row = b * 16 + (t >> 4);
    int c = t & 15;
    const float* src;
    if (row < NLB) src = lb + (size_t)row * DD;
    else if (row < NLB + NULB) src = an + (size_t)(row - NLB) * DD;
    else src = po + (size_t)(row - NLB - NULB) * DD;
    float4 v0 = ((const float4*)src)[c * 2];
    float4 v1 = ((const float4*)src)[c * 2 + 1];
    float ss = v0.x*v0.x + v0.y*v0.y + v0.z*v0.z + v0.w*v0.w
             + v1.x*v1.x + v1.y*v1.y + v1.z*v1.z + v1.w*v1.w;
#pragma unroll
    for (int off = 8; off >= 1; off >>= 1) ss += __shfl_xor(ss, off);
    float inv = SQRTC / fmaxf(sqrtf(ss), 1e-12f);
    union { bf16_t h[8]; uint4 u; } pk;
    pk.h[0] = (bf16_t)(v0.x*inv); pk.h[1] = (bf16_t)(v0.y*inv);
    pk.h[2] = (bf16_t)(v0.z*inv); pk.h[3] = (bf16_t)(v0.w*inv);
    pk.h[4] = (bf16_t)(v1.x*inv); pk.h[5] = (bf16_t)(v1.y*inv);
    pk.h[6] = (bf16_t)(v1.z*inv); pk.h[7] = (bf16_t)(v1.w*inv);
    *(uint4*)(F + fidx(row, c)) = pk.u;
    return;
  }

  // ---- V build: 256 rows/block over all 16384 output rows ----
  if (t < NC) lcnt[t] = 0.0f;
  __syncthreads();
  int gid = (b - 1024) * 256 + t;
  float p[16];
  p[10] = 1.0f; p[11] = 0.f; p[12] = 0.f; p[13] = 0.f; p[14] = 0.f; p[15] = 0.f;
  if (gid < NLB) {
    int idx = 0;
#pragma unroll
    for (int c = 0; c < NC; ++c) {
      p[c] = onehot[(size_t)gid * NC + c];
      if (p[c] == 1.0f) idx = c;
    }
    atomicAdd(&lcnt[idx], 1.0f);
  } else {
    int r = (gid < NLB + NULB) ? (gid - NLB) : (gid - NLB - NULB);
    bool count = (gid < NLB + NULB);
    float a[NC], bb[NC];
#pragma unroll
    for (int c = 0; c < NC; ++c) { a[c] = l1[(size_t)r * NC + c]; bb[c] = l2[(size_t)r * NC + c]; }
    float m1 = a[0], m2 = bb[0];
#pragma unroll
    for (int c = 1; c < NC; ++c) { m1 = fmaxf(m1, a[c]); m2 = fmaxf(m2, bb[c]); }
    float s1 = 0.0f, s2 = 0.0f;
#pragma unroll
    for (int c = 0; c < NC; ++c) {
      s1 += expf(2.0f * (a[c] - m1));
      s2 += expf(2.0f * (bb[c] - m2));
    }
    bool take1 = (s1 <= s2);  // max(prob1)=1/s1 >= 1/s2=max(prob2)
    float g[NC];
#pragma unroll
    for (int c = 0; c < NC; ++c) g[c] = take1 ? a[c] : bb[c];
    float mg = g[0];
#pragma unroll
    for (int c = 1; c < NC; ++c) mg = fmaxf(mg, g[c]);
    float e[NC]; float sg = 0.0f;
#pragma unroll
    for (int c = 0; c < NC; ++c) { e[c] = expf(g[c] - mg); sg += e[c]; }
    float msk[NC];
#pragma unroll
    for (int c = 0; c < NC; ++c) msk[c] = ((e[c] / sg) >= 0.95f) ? g[c] : 0.0f;
    float mx = msk[0]; int mi = 0;
#pragma unroll
    for (int c = 1; c < NC; ++c) if (msk[c] > mx) { mx = msk[c]; mi = c; }
    if (count && mx != 0.0f) atomicAdd(&lcnt[mi], 2.0f);
    float mm = 2.0f * msk[0];
#pragma unroll
    for (int c = 1; c < NC; ++c) mm = fmaxf(mm, 2.0f * msk[c]);
    float q[NC]; float sp = 0.0f;
#pragma unroll
    for (int c = 0; c < NC; ++c) { q[c] = expf(2.0f * msk[c] - mm); sp += q[c]; }
#pragma unroll
    for (int c = 0; c < NC; ++c) p[c] = q[c] / sp;
  }
#pragma unroll
  for (int c = 0; c < 16; ++c) Vtmp[t * 16 + c] = p[c];
  __syncthreads();
  if (t < 16) clsPart[(size_t)(b - 1024) * 16 + t] = (t < NC) ? lcnt[t] : 0.0f;
  // scatter to VF frag layout: 1024 16B chunks, 4 per thread (coalesced)
  int gbase = (b - 1024) * 16;
#pragma unroll
  for (int u = 0; u < 4; ++u) {
    int cid = t * 4 + u;         // 0..1023
    int gl = cid >> 6;           // local group 0..15
    int l  = cid & 63;
    int q  = l >> 4;
    int n  = l & 15;
    union { bf16_t h[8]; uint4 uu; } pk;
#pragma unroll
    for (int d = 0; d < 4; ++d) {
      float v = Vtmp[(gl * 16 + q * 4 + d) * 16 + n];
      bf16_t hi = (bf16_t)v;
      pk.h[d] = hi;
      pk.h[4 + d] = (bf16_t)(v - (float)hi);
    }
    *(uint4*)(VF + ((size_t)(gbase + gl) * 64 + l) * 8) = pk.uu;
  }
}

// ================= attention partials =================
// R9 structure (known-good 76.6us, exactly at the 128-reg budget -- R10's
// paired-PV spilled to scratch and went HBM-bound). Two issue-cycle cuts:
// (1) pack = fma + cvt_pknorm_i16 (one op packs two rounded bf16 weights),
// (2) first QK MFMA takes a persistent zero tuple as C (no per-tile movs).
// QK: mfma_16x16x32_bf16 (F pre-scaled: w = 2^cfr).
// PV: one MFMA per i-set, P replicated {p01,p23,p01,p23} against V frags
// {hi0..3, lo0..3} (compensated bf16 split). LDS 40960 -> 4 blocks/CU.
__launch_bounds__(256, 4)
__global__ void kattn(const bf16_t* __restrict__ F, const bf16_t* __restrict__ VF,
                      float* __restrict__ P12) {
  __shared__ bf16_t Fs[BJ * 128];            // 32 KB, swizzled tile image
  __shared__ bf16_t Vs[(BJ / 16) * 512];     // 8 KB interleaved hi/lo frags
  int t = threadIdx.x;
  int lane = t & 63;
  int wave = t >> 6;    // 0..3
  int q = lane >> 4;    // 0..3
  int r = lane & 15;    // 0..15
  int i0 = blockIdx.x * BI + wave * 64;
  int jbase = blockIdx.y * JSEG;

  // stationary B-frags: 4 i-sets x 16 rows (from swizzled global layout)
  bf16x8 bfr[4][4];
#pragma unroll
  for (int s = 0; s < 4; ++s)
#pragma unroll
    for (int kk = 0; kk < 4; ++kk)
      bfr[s][kk] = *(const bf16x8*)(F + fidx(i0 + s * 16 + r, kk * 4 + q));

  f32x4 acc[4];
#pragma unroll
  for (int s = 0; s < 4; ++s) acc[s] = (f32x4){0.f, 0.f, 0.f, 0.f};
  const f32x4 kZero = {0.f, 0.f, 0.f, 0.f};  // persistent zero C-operand

  for (int jt = 0; jt < JSEG; jt += BJ) {
    int j0 = jbase + jt;
    __syncthreads();
    // ---- async stage F tile (32 KB) + V tile (8 KB), 10 instrs/wave ----
    {
      const uint4* srcF = (const uint4*)(F + ((size_t)(j0 >> 7) << 14));
#pragma unroll
      for (int k = 0; k < 8; ++k) {
        int off = ((k * 4 + wave) << 6) + lane;   // 16B-chunk idx 0..2047
        __builtin_amdgcn_global_load_lds(
            (const __attribute__((address_space(1))) uint4*)(srcF + off),
            (__attribute__((address_space(3))) uint4*)((uint4*)Fs + off), 16, 0, 0);
      }
      const uint4* srcV = (const uint4*)(VF + ((size_t)(j0 >> 4) << 9));
#pragma unroll
      for (int k = 0; k < 2; ++k) {
        int off = ((k * 4 + wave) << 6) + lane;   // 0..511
        __builtin_amdgcn_global_load_lds(
            (const __attribute__((address_space(1))) uint4*)(srcV + off),
            (__attribute__((address_space(3))) uint4*)((uint4*)Vs + off), 16, 0, 0);
      }
    }
    __syncthreads();  // implicit vmcnt(0) drain: data resident

#pragma unroll
    for (int jj = 0; jj < BJ / 16; ++jj) {
      // A-frags for this 16-row j-chunk (shared across the 4 i-sets)
      bf16x8 afr[4];
      const bf16_t* fsrow = &Fs[(jj * 16 + r) * 128];
#pragma unroll
      for (int kk = 0; kk < 4; ++kk)
        afr[kk] = *(const bf16x8*)(fsrow + ((kk * 4 + q) ^ r) * 8);
      // V B-frag (hi at k-idx 0..3, lo at 4..7) for this j-chunk
      bf16x8 bv = *(const bf16x8*)&Vs[jj * 512 + lane * 8];
#pragma unroll
      for (int s = 0; s < 4; ++s) {
        f32x4 cfr = __builtin_amdgcn_mfma_f32_16x16x32_bf16(afr[0], bfr[s][0], kZero, 0, 0, 0);
#pragma unroll
        for (int kk = 1; kk < 4; ++kk)
          cfr = __builtin_amdgcn_mfma_f32_16x16x32_bf16(afr[kk], bfr[s][kk], cfr, 0, 0, 0);
        union { u32 u[4]; bf16x8 v; } pf;
        pf.u[0] = packexp2bf(cfr[0], cfr[1]);
        pf.u[1] = packexp2bf(cfr[2], cfr[3]);
        pf.u[2] = pf.u[0];
        pf.u[3] = pf.u[1];
        acc[s] = __builtin_amdgcn_mfma_f32_16x16x32_bf16(pf.v, bv, acc[s], 0, 0, 0);
      }
    }
  }

  // acc[s] lane(q,r) reg rg = partial[row = i0+s*16+q*4+rg][col = r]
  if (r < 11) {
#pragma unroll
    for (int s = 0; s < 4; ++s) {
      float* op = P12 + (size_t)(i0 + s * 16 + q * 4) * VW + r;
      atomicAdd(&op[0 * VW], acc[s][0]);
      atomicAdd(&op[1 * VW], acc[s][1]);
      atomicAdd(&op[2 * VW], acc[s][2]);
      atomicAdd(&op[3 * VW], acc[s][3]);
    }
  }
}

// ---------------- finalize: class-count reduce + divides ----------------
__global__ void kfinal(float* __restrict__ out, const float* __restrict__ P12,
                       const float* __restrict__ clsPart) {
  __shared__ float clsS[16];
  int t = threadIdx.x;
  if (t < 64) {
    const float4* cp = (const float4*)clsPart;  // 64 rows x 4 float4
    float4 c0 = cp[t * 4], c1 = cp[t * 4 + 1], c2 = cp[t * 4 + 2], c3 = cp[t * 4 + 3];
#pragma unroll
    for (int off = 32; off >= 1; off >>= 1) {
      c0.x += __shfl_xor(c0.x, off); c0.y += __shfl_xor(c0.y, off);
      c0.z += __shfl_xor(c0.z, off); c0.w += __shfl_xor(c0.w, off);
      c1.x += __shfl_xor(c1.x, off); c1.y += __shfl_xor(c1.y, off);
      c1.z += __shfl_xor(c1.z, off); c1.w += __shfl_xor(c1.w, off);
      c2.x += __shfl_xor(c2.x, off); c2.y += __shfl_xor(c2.y, off);
    }
    if (t == 0) {
      *(float4*)&clsS[0] = c0;
      *(float4*)&clsS[4] = c1;
      clsS[8] = c2.x; clsS[9] = c2.y;
      clsS[10] = 0.f; clsS[11] = 0.f; clsS[12] = 0.f;
      clsS[13] = 0.f; clsS[14] = 0.f; clsS[15] = 0.f;
    }
  }
  __syncthreads();
  float d[NC]; float tot = 0.0f;
#pragma unroll
  for (int c = 0; c < NC; ++c) { d[c] = clsS[c]; tot += d[c]; }
  int row = blockIdx.x * 256 + t;  // 64 blocks x 256
  const float* pr = P12 + (size_t)row * VW;
  float rs = 1.0f / pr[10];
  float* op = out + (size_t)row * NC;
#pragma unroll
  for (int c = 0; c < NC; ++c) {
    float den = (d[c] == 0.0f) ? tot : d[c];
    op[c] = pr[c] * rs / den;
  }
}

extern "C" void kernel_launch(void* const* d_in, const int* in_sizes, int n_in,
                              void* d_out, int out_size, void* d_ws, size_t ws_size,
                              hipStream_t stream) {
  const float* anchor   = (const float*)d_in[0];  // 6144x128
  const float* positive = (const float*)d_in[1];  // 6144x128
  const float* lbfeat   = (const float*)d_in[2];  // 4096x128
  const float* onehot   = (const float*)d_in[3];  // 4096x10
  const float* l1       = (const float*)d_in[4];  // 6144x10
  const float* l2       = (const float*)d_in[5];  // 6144x10
  float* out = (float*)d_out;                     // 16384x10

  char* ws = (char*)d_ws;
  bf16_t* F       = (bf16_t*)ws;                               // 4 MiB (swizzled tiles)
  bf16_t* VF      = (bf16_t*)(ws + 4194304);                   // 1 MiB (frag layout)
  float*  P12     = (float*)(ws + 4194304 + 1048576);          // 768 KiB
  float*  clsPart = (float*)(ws + 4194304 + 1048576 + 786432); // 4 KiB

  kprep2<<<1088, 256, 0, stream>>>(lbfeat, anchor, positive, onehot, l1, l2,
                                   F, VF, clsPart, P12);
  kattn<<<dim3(NROWS / BI, SEG), 256, 0, stream>>>(F, VF, P12);
  kfinal<<<NROWS / 256, 256, 0, stream>>>(out, P12, clsPart);
}

// Round 12
// 121.403 us; speedup vs baseline: 1.7240x; 1.1684x over previous
//
#include <hip/hip_runtime.h>
#include <hip/hip_bf16.h>

#define NLB 4096
#define NULB 6144
#define NROWS 16384   // 4096 + 2*6144
#define DD 128
#define NC 10
#define VW 12                // P12 row width: 10 numerators + denom + pad
#define SEG 16
#define JSEG (NROWS / SEG)   // 1024
#define BI 256               // i-rows per block (4 waves x 64)
#define BJ 128               // j-rows per LDS tile
#define SQRTC 1.6986437f     // sqrt(2*log2(e))
// F stored as fp8 of (16*SQRTC*f)  ->  QK result cfr = 256 * C * dot
// pack: bf16 bits of 2^(cfr/256) ~= round(0.5*cfr + 16250.42)
#define FE_BIAS  1.06498747e9f   // (127-0.0436)*2^23  (f32 fallback path)

typedef __bf16 bf16_t;
typedef bf16_t bf16x8 __attribute__((ext_vector_type(8)));
typedef float f32x4 __attribute__((ext_vector_type(4)));
typedef short i16x2 __attribute__((ext_vector_type(2)));
typedef int i32x8 __attribute__((ext_vector_type(8)));
typedef unsigned int u32;
typedef unsigned char u8;

// fp8 F global layout = swizzled LDS image, 128-row tiles of 128-byte rows:
//   byte address(row, 16B-chunk c0..7) =
//     (row>>7)*16384 + (row&127)*128 + ((c ^ (row&7)) << 4)
__device__ __forceinline__ size_t f8idx(int row, int c) {
  return ((size_t)(row >> 7) << 14) + (size_t)((row & 127) << 7)
       + (size_t)(((c ^ (row & 7)) & 7) << 4);
}

// pack two bf16(2^(c/256)) into one dword (one fma + one pknorm each pair).
// bf16 bits of 2^x = round(128x + 16250.42); here x = c/256 -> 0.5*c.
// pknorm: i16 = round(y*32767) -> y = c*(0.5/32767) + 16250.42/32767.
__device__ __forceinline__ u32 packexp2bf(float c0, float c1) {
#if __has_builtin(__builtin_amdgcn_cvt_pknorm_i16)
  float y0 = fmaf(c0, 1.5259021e-5f, 0.49593857f);
  float y1 = fmaf(c1, 1.5259021e-5f, 0.49593857f);
  union { i16x2 p; u32 u; } cv;
  cv.p = __builtin_amdgcn_cvt_pknorm_i16(y0, y1);
  return cv.u;
#else
  u32 b0 = (u32)(int)fmaf(c0, 32768.0f, FE_BIAS);   // 2^23/256
  u32 b1 = (u32)(int)fmaf(c1, 32768.0f, FE_BIAS);
  return __builtin_amdgcn_perm(b1, b0, 0x07060302u);
#endif
}

// ================= fused prep =================
// blocks 0..1023   : L2-normalize 16 rows each of [lb;anchor;pos], scale by
//                    16*SQRTC, convert to fp8 e4m3 into the swizzled F image;
//                    also zero 192 floats of P12 each.
// blocks 1024..1087: build V fragments (interleaved hi/lo bf16) + per-block
//                    class-count partials.
__global__ void kprep2(const float* __restrict__ lb, const float* __restrict__ an,
                       const float* __restrict__ po, const float* __restrict__ onehot,
                       const float* __restrict__ l1, const float* __restrict__ l2,
                       u8* __restrict__ F8, bf16_t* __restrict__ VF,
                       float* __restrict__ clsPart, float* __restrict__ P12) {
  __shared__ float Vtmp[256 * 16];
  __shared__ float lcnt[NC];
  int b = blockIdx.x;
  int t = threadIdx.x;

  if (b < 1024) {
    if (t < 192) P12[(size_t)b * 192 + t] = 0.0f;  // 1024*192 = NROWS*VW
    int row = b * 16 + (t >> 4);
    int c = t & 15;           // lane's 8 floats = k bytes c*8 .. c*8+7
    const float* src;
    if (row < NLB) src = lb + (size_t)row * DD;
    else if (row < NLB + NULB) src = an + (size_t)(row - NLB) * DD;
    else src = po + (size_t)(row - NLB - NULB) * DD;
    float4 v0 = ((const float4*)src)[c * 2];
    float4 v1 = ((const float4*)src)[c * 2 + 1];
    float ss = v0.x*v0.x + v0.y*v0.y + v0.z*v0.z + v0.w*v0.w
             + v1.x*v1.x + v1.y*v1.y + v1.z*v1.z + v1.w*v1.w;
#pragma unroll
    for (int off = 8; off >= 1; off >>= 1) ss += __shfl_xor(ss, off);
    float inv = (16.0f * SQRTC) / fmaxf(sqrtf(ss), 1e-12f);
    u32 d0 = (u32)__builtin_amdgcn_cvt_pk_fp8_f32(v0.x*inv, v0.y*inv, 0, false);
    d0 = (u32)__builtin_amdgcn_cvt_pk_fp8_f32(v0.z*inv, v0.w*inv, d0, true);
    u32 d1 = (u32)__builtin_amdgcn_cvt_pk_fp8_f32(v1.x*inv, v1.y*inv, 0, false);
    d1 = (u32)__builtin_amdgcn_cvt_pk_fp8_f32(v1.z*inv, v1.w*inv, d1, true);
    uint2 dd = {d0, d1};
    // chunk = c>>1 (16B), byte-in-chunk = (c&1)*8
    *(uint2*)(F8 + f8idx(row, c >> 1) + ((c & 1) << 3)) = dd;
    return;
  }

  // ---- V build: 256 rows/block over all 16384 output rows ----
  if (t < NC) lcnt[t] = 0.0f;
  __syncthreads();
  int gid = (b - 1024) * 256 + t;
  float p[16];
  p[10] = 1.0f; p[11] = 0.f; p[12] = 0.f; p[13] = 0.f; p[14] = 0.f; p[15] = 0.f;
  if (gid < NLB) {
    int idx = 0;
#pragma unroll
    for (int c = 0; c < NC; ++c) {
      p[c] = onehot[(size_t)gid * NC + c];
      if (p[c] == 1.0f) idx = c;
    }
    atomicAdd(&lcnt[idx], 1.0f);
  } else {
    int r = (gid < NLB + NULB) ? (gid - NLB) : (gid - NLB - NULB);
    bool count = (gid < NLB + NULB);
    float a[NC], bb[NC];
#pragma unroll
    for (int c = 0; c < NC; ++c) { a[c] = l1[(size_t)r * NC + c]; bb[c] = l2[(size_t)r * NC + c]; }
    float m1 = a[0], m2 = bb[0];
#pragma unroll
    for (int c = 1; c < NC; ++c) { m1 = fmaxf(m1, a[c]); m2 = fmaxf(m2, bb[c]); }
    float s1 = 0.0f, s2 = 0.0f;
#pragma unroll
    for (int c = 0; c < NC; ++c) {
      s1 += expf(2.0f * (a[c] - m1));
      s2 += expf(2.0f * (bb[c] - m2));
    }
    bool take1 = (s1 <= s2);  // max(prob1)=1/s1 >= 1/s2=max(prob2)
    float g[NC];
#pragma unroll
    for (int c = 0; c < NC; ++c) g[c] = take1 ? a[c] : bb[c];
    float mg = g[0];
#pragma unroll
    for (int c = 1; c < NC; ++c) mg = fmaxf(mg, g[c]);
    float e[NC]; float sg = 0.0f;
#pragma unroll
    for (int c = 0; c < NC; ++c) { e[c] = expf(g[c] - mg); sg += e[c]; }
    float msk[NC];
#pragma unroll
    for (int c = 0; c < NC; ++c) msk[c] = ((e[c] / sg) >= 0.95f) ? g[c] : 0.0f;
    float mx = msk[0]; int mi = 0;
#pragma unroll
    for (int c = 1; c < NC; ++c) if (msk[c] > mx) { mx = msk[c]; mi = c; }
    if (count && mx != 0.0f) atomicAdd(&lcnt[mi], 2.0f);
    float mm = 2.0f * msk[0];
#pragma unroll
    for (int c = 1; c < NC; ++c) mm = fmaxf(mm, 2.0f * msk[c]);
    float q[NC]; float sp = 0.0f;
#pragma unroll
    for (int c = 0; c < NC; ++c) { q[c] = expf(2.0f * msk[c] - mm); sp += q[c]; }
#pragma unroll
    for (int c = 0; c < NC; ++c) p[c] = q[c] / sp;
  }
#pragma unroll
  for (int c = 0; c < 16; ++c) Vtmp[t * 16 + c] = p[c];
  __syncthreads();
  if (t < 16) clsPart[(size_t)(b - 1024) * 16 + t] = (t < NC) ? lcnt[t] : 0.0f;
  // scatter to VF frag layout: 1024 16B chunks, 4 per thread (coalesced)
  int gbase = (b - 1024) * 16;
#pragma unroll
  for (int u = 0; u < 4; ++u) {
    int cid = t * 4 + u;         // 0..1023
    int gl = cid >> 6;           // local group 0..15
    int l  = cid & 63;
    int q  = l >> 4;
    int n  = l & 15;
    union { bf16_t h[8]; uint4 uu; } pk;
#pragma unroll
    for (int d = 0; d < 4; ++d) {
      float v = Vtmp[(gl * 16 + q * 4 + d) * 16 + n];
      bf16_t hi = (bf16_t)v;
      pk.h[d] = hi;
      pk.h[4 + d] = (bf16_t)(v - (float)hi);
    }
    *(uint4*)(VF + ((size_t)(gbase + gl) * 64 + l) * 8) = pk.uu;
  }
}

// ================= attention partials =================
// QK: mfma_scale_f32_16x16x128_f8f6f4 (MX fp8, 2x bf16 rate) -- ONE MFMA per
// 16x16 tile covers all K=128. A and B frags use identical byte patterns from
// F rows, so QK's symmetric pair-sum is correct under any consistent internal
// k-permutation; C/D layout is shape-determined (== 16x16 bf16), so the R11
// pack / PV / atomic tail are unchanged. Scales = 1.0 (0x7F), e4m3 (fmt 0).
// PV: one bf16 MFMA per i-set, P {p01,p23,p01,p23} vs V {hi0..3, lo0..3}.
// LDS 24576 B (16K fp8 F tile + 8K V frags); grid 1024 = 4 blocks/CU exact.
__launch_bounds__(256, 4)
__global__ void kattn(const u8* __restrict__ F8, const bf16_t* __restrict__ VF,
                      float* __restrict__ P12) {
  __shared__ u8 Fs[BJ * 128];                // 16 KB fp8 swizzled tile image
  __shared__ bf16_t Vs[(BJ / 16) * 512];     // 8 KB interleaved hi/lo frags
  int t = threadIdx.x;
  int lane = t & 63;
  int wave = t >> 6;    // 0..3
  int q = lane >> 4;    // 0..3
  int r = lane & 15;    // 0..15
  int i0 = blockIdx.x * BI + wave * 64;
  int jbase = blockIdx.y * JSEG;

  // stationary B-frags: 4 i-sets, 32 fp8 bytes/lane (chunks 2q, 2q+1 of row)
  i32x8 bfr[4];
#pragma unroll
  for (int s = 0; s < 4; ++s) {
    int row = i0 + s * 16 + r;
    union { uint4 h[2]; i32x8 v; } bb;
    bb.h[0] = *(const uint4*)(F8 + f8idx(row, 2 * q));
    bb.h[1] = *(const uint4*)(F8 + f8idx(row, 2 * q + 1));
    bfr[s] = bb.v;
  }

  f32x4 acc[4];
#pragma unroll
  for (int s = 0; s < 4; ++s) acc[s] = (f32x4){0.f, 0.f, 0.f, 0.f};
  const f32x4 kZero = {0.f, 0.f, 0.f, 0.f};

  for (int jt = 0; jt < JSEG; jt += BJ) {
    int j0 = jbase + jt;
    __syncthreads();
    // ---- async stage F tile (16 KB, 4 instr/wave) + V tile (8 KB, 2) ----
    {
      const uint4* srcF = (const uint4*)(F8 + ((size_t)(j0 >> 7) << 14));
#pragma unroll
      for (int k = 0; k < 4; ++k) {
        int off = ((k * 4 + wave) << 6) + lane;   // 16B-chunk idx 0..1023
        __builtin_amdgcn_global_load_lds(
            (const __attribute__((address_space(1))) uint4*)(srcF + off),
            (__attribute__((address_space(3))) uint4*)((uint4*)Fs + off), 16, 0, 0);
      }
      const uint4* srcV = (const uint4*)(VF + ((size_t)(j0 >> 4) << 9));
#pragma unroll
      for (int k = 0; k < 2; ++k) {
        int off = ((k * 4 + wave) << 6) + lane;   // 0..511
        __builtin_amdgcn_global_load_lds(
            (const __attribute__((address_space(1))) uint4*)(srcV + off),
            (__attribute__((address_space(3))) uint4*)((uint4*)Vs + off), 16, 0, 0);
      }
    }
    __syncthreads();  // implicit vmcnt(0) drain: data resident

#pragma unroll
    for (int jj = 0; jj < BJ / 16; ++jj) {
      // A-frag: 32 fp8 bytes of row jj*16+r (chunks 2q, 2q+1, swizzled)
      union { uint4 h[2]; i32x8 v; } af;
      const u8* fsrow = &Fs[(jj * 16 + r) * 128];
      af.h[0] = *(const uint4*)(fsrow + ((((2 * q) ^ (r & 7)) & 7) << 4));
      af.h[1] = *(const uint4*)(fsrow + ((((2 * q + 1) ^ (r & 7)) & 7) << 4));
      // V B-frag (hi at k-idx 0..3, lo at 4..7) for this j-chunk
      bf16x8 bv = *(const bf16x8*)&Vs[jj * 512 + lane * 8];
#pragma unroll
      for (int s = 0; s < 4; ++s) {
        f32x4 cfr = __builtin_amdgcn_mfma_scale_f32_16x16x128_f8f6f4(
            af.v, bfr[s], kZero, 0, 0, 0, 0x7F7F7F7Fu, 0, 0x7F7F7F7Fu);
        union { u32 u[4]; bf16x8 v; } pf;
        pf.u[0] = packexp2bf(cfr[0], cfr[1]);
        pf.u[1] = packexp2bf(cfr[2], cfr[3]);
        pf.u[2] = pf.u[0];
        pf.u[3] = pf.u[1];
        acc[s] = __builtin_amdgcn_mfma_f32_16x16x32_bf16(pf.v, bv, acc[s], 0, 0, 0);
      }
    }
  }

  // acc[s] lane(q,r) reg rg = partial[row = i0+s*16+q*4+rg][col = r]
  if (r < 11) {
#pragma unroll
    for (int s = 0; s < 4; ++s) {
      float* op = P12 + (size_t)(i0 + s * 16 + q * 4) * VW + r;
      atomicAdd(&op[0 * VW], acc[s][0]);
      atomicAdd(&op[1 * VW], acc[s][1]);
      atomicAdd(&op[2 * VW], acc[s][2]);
      atomicAdd(&op[3 * VW], acc[s][3]);
    }
  }
}

// ---------------- finalize: class-count reduce + divides ----------------
__global__ void kfinal(float* __restrict__ out, const float* __restrict__ P12,
                       const float* __restrict__ clsPart) {
  __shared__ float clsS[16];
  int t = threadIdx.x;
  if (t < 64) {
    const float4* cp = (const float4*)clsPart;  // 64 rows x 4 float4
    float4 c0 = cp[t * 4], c1 = cp[t * 4 + 1], c2 = cp[t * 4 + 2], c3 = cp[t * 4 + 3];
#pragma unroll
    for (int off = 32; off >= 1; off >>= 1) {
      c0.x += __shfl_xor(c0.x, off); c0.y += __shfl_xor(c0.y, off);
      c0.z += __shfl_xor(c0.z, off); c0.w += __shfl_xor(c0.w, off);
      c1.x += __shfl_xor(c1.x, off); c1.y += __shfl_xor(c1.y, off);
      c1.z += __shfl_xor(c1.z, off); c1.w += __shfl_xor(c1.w, off);
      c2.x += __shfl_xor(c2.x, off); c2.y += __shfl_xor(c2.y, off);
    }
    if (t == 0) {
      *(float4*)&clsS[0] = c0;
      *(float4*)&clsS[4] = c1;
      clsS[8] = c2.x; clsS[9] = c2.y;
      clsS[10] = 0.f; clsS[11] = 0.f; clsS[12] = 0.f;
      clsS[13] = 0.f; clsS[14] = 0.f; clsS[15] = 0.f;
    }
  }
  __syncthreads();
  float d[NC]; float tot = 0.0f;
#pragma unroll
  for (int c = 0; c < NC; ++c) { d[c] = clsS[c]; tot += d[c]; }
  int row = blockIdx.x * 256 + t;  // 64 blocks x 256
  const float* pr = P12 + (size_t)row * VW;
  float rs = 1.0f / pr[10];
  float* op = out + (size_t)row * NC;
#pragma unroll
  for (int c = 0; c < NC; ++c) {
    float den = (d[c] == 0.0f) ? tot : d[c];
    op[c] = pr[c] * rs / den;
  }
}

extern "C" void kernel_launch(void* const* d_in, const int* in_sizes, int n_in,
                              void* d_out, int out_size, void* d_ws, size_t ws_size,
                              hipStream_t stream) {
  const float* anchor   = (const float*)d_in[0];  // 6144x128
  const float* positive = (const float*)d_in[1];  // 6144x128
  const float* lbfeat   = (const float*)d_in[2];  // 4096x128
  const float* onehot   = (const float*)d_in[3];  // 4096x10
  const float* l1       = (const float*)d_in[4];  // 6144x10
  const float* l2       = (const float*)d_in[5];  // 6144x10
  float* out = (float*)d_out;                     // 16384x10

  char* ws = (char*)d_ws;
  u8*     F8      = (u8*)ws;                                   // 2 MiB fp8 swizzled image
  bf16_t* VF      = (bf16_t*)(ws + 2097152);                   // 1 MiB (frag layout)
  float*  P12     = (float*)(ws + 2097152 + 1048576);          // 768 KiB
  float*  clsPart = (float*)(ws + 2097152 + 1048576 + 786432); // 4 KiB

  kprep2<<<1088, 256, 0, stream>>>(lbfeat, anchor, positive, onehot, l1, l2,
                                   F8, VF, clsPart, P12);
  kattn<<<dim3(NROWS / BI, SEG), 256, 0, stream>>>(F8, VF, P12);
  kfinal<<<NROWS / 256, 256, 0, stream>>>(out, P12, clsPart);
}

// Round 13
// 113.369 us; speedup vs baseline: 1.8462x; 1.0709x over previous
//
#include <hip/hip_runtime.h>
#include <hip/hip_bf16.h>

#define NLB 4096
#define NULB 6144
#define NROWS 16384   // 4096 + 2*6144
#define DD 128
#define NC 10
#define VW 12                // P12 row width: 10 numerators + denom + pad
#define SEG 16
#define JSEG (NROWS / SEG)   // 1024
#define BI 256               // i-rows per block (4 waves x 64)
#define BJ 128               // j-rows per LDS tile
#define SQRTC 1.6986437f     // sqrt(2*log2(e))
// F stored as fp8 of (16*SQRTC*f)  ->  QK result cfr = 256 * C * dot
#define FE_BIAS  1.06498747e9f   // f32 fallback bias

typedef __bf16 bf16_t;
typedef _Float16 f16_t;
typedef f16_t f16x8 __attribute__((ext_vector_type(8)));
typedef float f32x4 __attribute__((ext_vector_type(4)));
typedef short i16x2 __attribute__((ext_vector_type(2)));
typedef int i32x8 __attribute__((ext_vector_type(8)));
typedef unsigned int u32;
typedef unsigned char u8;

// fp8 F global layout = swizzled LDS image, 128-row tiles of 128-byte rows:
//   byte address(row, 16B-chunk c0..7) =
//     (row>>7)*16384 + (row&127)*128 + ((c ^ (row&7)) << 4)
__device__ __forceinline__ size_t f8idx(int row, int c) {
  return ((size_t)(row >> 7) << 14) + (size_t)((row & 127) << 7)
       + (size_t)(((c ^ (row & 7)) & 7) << 4);
}

// pack two f16(2^(c/256)) into one dword (fma + pknorm per pair).
// f16 bits of 2^x ~= round(1024x + 15315.35); x = c/256 -> 4*c.
// pknorm: i16 = round(y*32767) -> y = c*(4/32767) + 15315.35/32767.
// staircase rel err ~0.2%, mean-zero, common-mode num/denom (R9/R11/R12
// all absmax-neutral with coarser variants).
__device__ __forceinline__ u32 packexp2f16(float c0, float c1) {
#if __has_builtin(__builtin_amdgcn_cvt_pknorm_i16)
  float y0 = fmaf(c0, 1.2207465e-4f, 0.46740490f);
  float y1 = fmaf(c1, 1.2207465e-4f, 0.46740490f);
  union { i16x2 p; u32 u; } cv;
  cv.p = __builtin_amdgcn_cvt_pknorm_i16(y0, y1);
  return cv.u;
#else
  u32 b0 = (u32)(int)fmaf(c0, 4.0f, 15315.354f);
  u32 b1 = (u32)(int)fmaf(c1, 4.0f, 15315.354f);
  return __builtin_amdgcn_perm(b1, b0, 0x05040100u);
#endif
}

// ================= fused prep =================
// blocks 0..1023   : L2-normalize 16 rows each of [lb;anchor;pos], scale by
//                    16*SQRTC, fp8 e4m3 into swizzled F image; zero P12 slice.
// blocks 1024..1087: build f16 V fragments (32-row pair-groups) + per-block
//                    class-count partials.
// VF layout: pair-group G (32 j-rows), lane l=(q=l>>4, n=l&15), 16B chunk:
//   f16 V[G*32 + q*4 + d][n] d=0..3, then f16 V[G*32+16 + q*4 + d][n] d=0..3
//   == f16 PV B-frag with k=q*8+{0..3} = even 16-chunk, {4..7} = odd.
__global__ void kprep2(const float* __restrict__ lb, const float* __restrict__ an,
                       const float* __restrict__ po, const float* __restrict__ onehot,
                       const float* __restrict__ l1, const float* __restrict__ l2,
                       u8* __restrict__ F8, f16_t* __restrict__ VF,
                       float* __restrict__ clsPart, float* __restrict__ P12) {
  __shared__ float Vtmp[256 * 16];
  __shared__ float lcnt[NC];
  int b = blockIdx.x;
  int t = threadIdx.x;

  if (b < 1024) {
    if (t < 192) P12[(size_t)b * 192 + t] = 0.0f;  // 1024*192 = NROWS*VW
    int row = b * 16 + (t >> 4);
    int c = t & 15;           // lane's 8 floats = k bytes c*8 .. c*8+7
    const float* src;
    if (row < NLB) src = lb + (size_t)row * DD;
    else if (row < NLB + NULB) src = an + (size_t)(row - NLB) * DD;
    else src = po + (size_t)(row - NLB - NULB) * DD;
    float4 v0 = ((const float4*)src)[c * 2];
    float4 v1 = ((const float4*)src)[c * 2 + 1];
    float ss = v0.x*v0.x + v0.y*v0.y + v0.z*v0.z + v0.w*v0.w
             + v1.x*v1.x + v1.y*v1.y + v1.z*v1.z + v1.w*v1.w;
#pragma unroll
    for (int off = 8; off >= 1; off >>= 1) ss += __shfl_xor(ss, off);
    float inv = (16.0f * SQRTC) / fmaxf(sqrtf(ss), 1e-12f);
    u32 d0 = (u32)__builtin_amdgcn_cvt_pk_fp8_f32(v0.x*inv, v0.y*inv, 0, false);
    d0 = (u32)__builtin_amdgcn_cvt_pk_fp8_f32(v0.z*inv, v0.w*inv, d0, true);
    u32 d1 = (u32)__builtin_amdgcn_cvt_pk_fp8_f32(v1.x*inv, v1.y*inv, 0, false);
    d1 = (u32)__builtin_amdgcn_cvt_pk_fp8_f32(v1.z*inv, v1.w*inv, d1, true);
    uint2 dd = {d0, d1};
    *(uint2*)(F8 + f8idx(row, c >> 1) + ((c & 1) << 3)) = dd;
    return;
  }

  // ---- V build: 256 rows/block over all 16384 output rows ----
  if (t < NC) lcnt[t] = 0.0f;
  __syncthreads();
  int gid = (b - 1024) * 256 + t;
  float p[16];
  p[10] = 1.0f; p[11] = 0.f; p[12] = 0.f; p[13] = 0.f; p[14] = 0.f; p[15] = 0.f;
  if (gid < NLB) {
    int idx = 0;
#pragma unroll
    for (int c = 0; c < NC; ++c) {
      p[c] = onehot[(size_t)gid * NC + c];
      if (p[c] == 1.0f) idx = c;
    }
    atomicAdd(&lcnt[idx], 1.0f);
  } else {
    int r = (gid < NLB + NULB) ? (gid - NLB) : (gid - NLB - NULB);
    bool count = (gid < NLB + NULB);
    float a[NC], bb[NC];
#pragma unroll
    for (int c = 0; c < NC; ++c) { a[c] = l1[(size_t)r * NC + c]; bb[c] = l2[(size_t)r * NC + c]; }
    float m1 = a[0], m2 = bb[0];
#pragma unroll
    for (int c = 1; c < NC; ++c) { m1 = fmaxf(m1, a[c]); m2 = fmaxf(m2, bb[c]); }
    float s1 = 0.0f, s2 = 0.0f;
#pragma unroll
    for (int c = 0; c < NC; ++c) {
      s1 += expf(2.0f * (a[c] - m1));
      s2 += expf(2.0f * (bb[c] - m2));
    }
    bool take1 = (s1 <= s2);  // max(prob1)=1/s1 >= 1/s2=max(prob2)
    float g[NC];
#pragma unroll
    for (int c = 0; c < NC; ++c) g[c] = take1 ? a[c] : bb[c];
    float mg = g[0];
#pragma unroll
    for (int c = 1; c < NC; ++c) mg = fmaxf(mg, g[c]);
    float e[NC]; float sg = 0.0f;
#pragma unroll
    for (int c = 0; c < NC; ++c) { e[c] = expf(g[c] - mg); sg += e[c]; }
    float msk[NC];
#pragma unroll
    for (int c = 0; c < NC; ++c) msk[c] = ((e[c] / sg) >= 0.95f) ? g[c] : 0.0f;
    float mx = msk[0]; int mi = 0;
#pragma unroll
    for (int c = 1; c < NC; ++c) if (msk[c] > mx) { mx = msk[c]; mi = c; }
    if (count && mx != 0.0f) atomicAdd(&lcnt[mi], 2.0f);
    float mm = 2.0f * msk[0];
#pragma unroll
    for (int c = 1; c < NC; ++c) mm = fmaxf(mm, 2.0f * msk[c]);
    float q[NC]; float sp = 0.0f;
#pragma unroll
    for (int c = 0; c < NC; ++c) { q[c] = expf(2.0f * msk[c] - mm); sp += q[c]; }
#pragma unroll
    for (int c = 0; c < NC; ++c) p[c] = q[c] / sp;
  }
#pragma unroll
  for (int c = 0; c < 16; ++c) Vtmp[t * 16 + c] = p[c];
  __syncthreads();
  if (t < 16) clsPart[(size_t)(b - 1024) * 16 + t] = (t < NC) ? lcnt[t] : 0.0f;
  // scatter to VF f16 pair-frag layout: 512 16B chunks/block, 2 per thread
  int gbase = (b - 1024) * 8;   // 8 pair-groups of 32 rows per 256-row block
#pragma unroll
  for (int u = 0; u < 2; ++u) {
    int cid = u * 256 + t;       // 0..511
    int G = cid >> 6;            // local pair-group 0..7
    int l = cid & 63;
    int q = l >> 4;
    int n = l & 15;
    union { f16_t h[8]; uint4 uu; } pk;
#pragma unroll
    for (int d = 0; d < 4; ++d) {
      pk.h[d]     = (f16_t)Vtmp[(G * 32      + q * 4 + d) * 16 + n];
      pk.h[4 + d] = (f16_t)Vtmp[(G * 32 + 16 + q * 4 + d) * 16 + n];
    }
    *(uint4*)(VF + ((size_t)(gbase + G) * 64 + l) * 8) = pk.uu;
  }
}

// ================= attention partials =================
// Double-buffered tiles: stage tile jt+1 into the other LDS buffer BEFORE
// computing tile jt, so the compiler's vmcnt(0)-before-barrier drain waits on
// loads that overlapped the whole compute phase (R12 lost ~27% to that drain).
// QK: mfma_scale_f32_16x16x128_f8f6f4 per 16x16 tile (ONE mfma = all K=128).
// PV: even/odd 16-row chunks PAIRED in one mfma_f32_16x16x32_f16:
//   P_e -> k=q*8+0..3, P_o -> k=q*8+4..7, vs f16 V rows (single f16 V is
//   plenty: after /class-denom the quantization lands ~1e-9).
// LDS = 2*(16K F + 4K V) = 40960 exactly -> 4 blocks/CU, grid 1024, no tail.
__launch_bounds__(256, 4)
__global__ void kattn(const u8* __restrict__ F8, const f16_t* __restrict__ VF,
                      float* __restrict__ P12) {
  __shared__ u8 Fs[2][BJ * 128];       // 2 x 16 KB fp8 swizzled tile image
  __shared__ uint4 Vs4[2][256];        // 2 x 4 KB f16 V pair-frags
  int t = threadIdx.x;
  int lane = t & 63;
  int wave = t >> 6;    // 0..3
  int q = lane >> 4;    // 0..3
  int r = lane & 15;    // 0..15
  int i0 = blockIdx.x * BI + wave * 64;
  int jbase = blockIdx.y * JSEG;

  // stationary B-frags: 4 i-sets, 32 fp8 bytes/lane (chunks 2q, 2q+1 of row)
  i32x8 bfr[4];
#pragma unroll
  for (int s = 0; s < 4; ++s) {
    int row = i0 + s * 16 + r;
    union { uint4 h[2]; i32x8 v; } bb;
    bb.h[0] = *(const uint4*)(F8 + f8idx(row, 2 * q));
    bb.h[1] = *(const uint4*)(F8 + f8idx(row, 2 * q + 1));
    bfr[s] = bb.v;
  }

  f32x4 acc[4];
#pragma unroll
  for (int s = 0; s < 4; ++s) acc[s] = (f32x4){0.f, 0.f, 0.f, 0.f};
  const f32x4 kZero = {0.f, 0.f, 0.f, 0.f};

  // ---- staging helper (macro-ish lambdas keep the builtin addressing) ----
  auto stage = [&](int buf, int j0) {
    const uint4* srcF = (const uint4*)(F8 + ((size_t)(j0 >> 7) << 14));
#pragma unroll
    for (int k = 0; k < 4; ++k) {
      int off = ((k * 4 + wave) << 6) + lane;   // 16B-chunk idx 0..1023
      __builtin_amdgcn_global_load_lds(
          (const __attribute__((address_space(1))) uint4*)(srcF + off),
          (__attribute__((address_space(3))) uint4*)((uint4*)Fs[buf] + off), 16, 0, 0);
    }
    const uint4* srcV = (const uint4*)VF + ((size_t)(j0 >> 5) << 6);
    __builtin_amdgcn_global_load_lds(
        (const __attribute__((address_space(1))) uint4*)(srcV + t),
        (__attribute__((address_space(3))) uint4*)(Vs4[buf] + t), 16, 0, 0);
  };

  auto compute = [&](int buf) {
    const u8* fsb = Fs[buf];
    const uint4* vsb = Vs4[buf];
#pragma unroll
    for (int jp = 0; jp < 4; ++jp) {   // pairs of 16-row j-chunks
      union { uint4 h[2]; i32x8 v; } afe, afo;
      const u8* re = fsb + (jp * 32 + r) * 128;       // even chunk row
      const u8* ro = re + 16 * 128;                   // odd chunk row
      int c0 = (((2 * q) ^ (r & 7)) & 7) << 4;
      int c1 = (((2 * q + 1) ^ (r & 7)) & 7) << 4;
      afe.h[0] = *(const uint4*)(re + c0);
      afe.h[1] = *(const uint4*)(re + c1);
      afo.h[0] = *(const uint4*)(ro + c0);
      afo.h[1] = *(const uint4*)(ro + c1);
      union { uint4 qd; f16x8 v; } bv;
      bv.qd = vsb[jp * 64 + lane];
#pragma unroll
      for (int s = 0; s < 4; ++s) {
        f32x4 ce = __builtin_amdgcn_mfma_scale_f32_16x16x128_f8f6f4(
            afe.v, bfr[s], kZero, 0, 0, 0, 0x7F7F7F7Fu, 0, 0x7F7F7F7Fu);
        f32x4 co = __builtin_amdgcn_mfma_scale_f32_16x16x128_f8f6f4(
            afo.v, bfr[s], kZero, 0, 0, 0, 0x7F7F7F7Fu, 0, 0x7F7F7F7Fu);
        union { u32 u[4]; f16x8 v; } pf;
        pf.u[0] = packexp2f16(ce[0], ce[1]);
        pf.u[1] = packexp2f16(ce[2], ce[3]);
        pf.u[2] = packexp2f16(co[0], co[1]);
        pf.u[3] = packexp2f16(co[2], co[3]);
        acc[s] = __builtin_amdgcn_mfma_f32_16x16x32_f16(pf.v, bv.v, acc[s], 0, 0, 0);
      }
    }
  };

  // ---- double-buffered pipeline over the 8 tiles of this j-segment ----
  stage(0, jbase);
  __syncthreads();
#pragma unroll
  for (int jt = 0; jt < 7; ++jt) {
    stage((jt + 1) & 1, jbase + (jt + 1) * BJ);  // prefetch overlaps compute
    compute(jt & 1);
    __syncthreads();  // drain waits on loads that ran under compute
  }
  compute(1);

  // acc[s] lane(q,r) reg rg = partial[row = i0+s*16+q*4+rg][col = r]
  if (r < 11) {
#pragma unroll
    for (int s = 0; s < 4; ++s) {
      float* op = P12 + (size_t)(i0 + s * 16 + q * 4) * VW + r;
      atomicAdd(&op[0 * VW], acc[s][0]);
      atomicAdd(&op[1 * VW], acc[s][1]);
      atomicAdd(&op[2 * VW], acc[s][2]);
      atomicAdd(&op[3 * VW], acc[s][3]);
    }
  }
}

// ---------------- finalize: class-count reduce + divides ----------------
__global__ void kfinal(float* __restrict__ out, const float* __restrict__ P12,
                       const float* __restrict__ clsPart) {
  __shared__ float clsS[16];
  int t = threadIdx.x;
  if (t < 64) {
    const float4* cp = (const float4*)clsPart;  // 64 rows x 4 float4
    float4 c0 = cp[t * 4], c1 = cp[t * 4 + 1], c2 = cp[t * 4 + 2], c3 = cp[t * 4 + 3];
#pragma unroll
    for (int off = 32; off >= 1; off >>= 1) {
      c0.x += __shfl_xor(c0.x, off); c0.y += __shfl_xor(c0.y, off);
      c0.z += __shfl_xor(c0.z, off); c0.w += __shfl_xor(c0.w, off);
      c1.x += __shfl_xor(c1.x, off); c1.y += __shfl_xor(c1.y, off);
      c1.z += __shfl_xor(c1.z, off); c1.w += __shfl_xor(c1.w, off);
      c2.x += __shfl_xor(c2.x, off); c2.y += __shfl_xor(c2.y, off);
    }
    if (t == 0) {
      *(float4*)&clsS[0] = c0;
      *(float4*)&clsS[4] = c1;
      clsS[8] = c2.x; clsS[9] = c2.y;
      clsS[10] = 0.f; clsS[11] = 0.f; clsS[12] = 0.f;
      clsS[13] = 0.f; clsS[14] = 0.f; clsS[15] = 0.f;
    }
  }
  __syncthreads();
  float d[NC]; float tot = 0.0f;
#pragma unroll
  for (int c = 0; c < NC; ++c) { d[c] = clsS[c]; tot += d[c]; }
  int row = blockIdx.x * 256 + t;  // 64 blocks x 256
  const float* pr = P12 + (size_t)row * VW;
  float rs = 1.0f / pr[10];
  float* op = out + (size_t)row * NC;
#pragma unroll
  for (int c = 0; c < NC; ++c) {
    float den = (d[c] == 0.0f) ? tot : d[c];
    op[c] = pr[c] * rs / den;
  }
}

extern "C" void kernel_launch(void* const* d_in, const int* in_sizes, int n_in,
                              void* d_out, int out_size, void* d_ws, size_t ws_size,
                              hipStream_t stream) {
  const float* anchor   = (const float*)d_in[0];  // 6144x128
  const float* positive = (const float*)d_in[1];  // 6144x128
  const float* lbfeat   = (const float*)d_in[2];  // 4096x128
  const float* onehot   = (const float*)d_in[3];  // 4096x10
  const float* l1       = (const float*)d_in[4];  // 6144x10
  const float* l2       = (const float*)d_in[5];  // 6144x10
  float* out = (float*)d_out;                     // 16384x10

  char* ws = (char*)d_ws;
  u8*     F8      = (u8*)ws;                                   // 2 MiB fp8 swizzled image
  f16_t*  VF      = (f16_t*)(ws + 2097152);                    // 512 KiB f16 pair-frags
  float*  P12     = (float*)(ws + 2097152 + 524288);           // 768 KiB
  float*  clsPart = (float*)(ws + 2097152 + 524288 + 786432);  // 4 KiB

  kprep2<<<1088, 256, 0, stream>>>(lbfeat, anchor, positive, onehot, l1, l2,
                                   F8, VF, clsPart, P12);
  kattn<<<dim3(NROWS / BI, SEG), 256, 0, stream>>>(F8, VF, P12);
  kfinal<<<NROWS / 256, 256, 0, stream>>>(out, P12, clsPart);
}